// Round 16
// baseline (90.202 us; speedup 1.0000x reference)
//
#include <hip/hip_runtime.h>

#define HID 256
#define NB 8
#define SQL 2048
#define SKV 2048
#define SPLIT 4
#define KPB (SKV / SPLIT)   // 512 keys per (b,split) stream
#define KVB 32              // keys per staged tile
#define NT (KPB / KVB)      // 16 steps
#define NROW (NB * SQL)     // 16384 rows

typedef __attribute__((ext_vector_type(8))) short bf16x8;
typedef __attribute__((ext_vector_type(4))) float f32x4;

static __device__ __forceinline__ unsigned short f2bf(float x) {
  union { float f; unsigned int u; } v; v.f = x;
  unsigned int r = v.u + 0x7FFFu + ((v.u >> 16) & 1u);
  return (unsigned short)(r >> 16);
}

// ---------- P1: QKV projection (W converted f32->bf16 during LDS staging).
// Q,K row-major; V fragment-major (kappa key order)
// VF frag(b, tile, dt): lane(l15,g), j: V[key = tile*32 + 4g + (j&3) + 16*(j>>2)][dt*16 + l15]
__global__ __launch_bounds__(512, 2) void proj_kernel(
    const float* __restrict__ query, const float* __restrict__ key, const float* __restrict__ value,
    const float* __restrict__ Wq, const float* __restrict__ Wk, const float* __restrict__ Wv,
    const float* __restrict__ bq, const float* __restrict__ bk, const float* __restrict__ bv,
    unsigned short* __restrict__ Qb, unsigned short* __restrict__ Kr, unsigned short* __restrict__ VFo) {
  __shared__ __align__(16) char wl[65536];
  int tid = threadIdx.x;
  int wave = tid >> 6, lane = tid & 63, lr = lane & 15, lg = lane >> 4;
  int blk = blockIdx.x;        // 384 blocks
  int mat = blk >> 7;          // 0:Q 1:K 2:V
  int rem = blk & 127;
  int b = rem >> 4;
  int rt = rem & 15;

  const float* X = (mat == 0) ? query : (mat == 1 ? key : value);
  const float* Wf = (mat == 0) ? Wq : (mat == 1 ? Wk : Wv);
  const float* bias = (mat == 0) ? bq : (mat == 1 ? bk : bv);

  // A fragments once: 16 rows per wave, f32 -> bf16
  int row_a = rt * 128 + wave * 16 + lr;
  const float* xrow = X + ((size_t)(b * SQL + row_a)) * HID;
  bf16x8 af[8];
#pragma unroll
  for (int s = 0; s < 8; s++) {
    const float4* p = (const float4*)(xrow + s * 32 + lg * 8);
    float4 x0 = p[0], x1 = p[1];
    bf16x8 a;
    a[0] = (short)f2bf(x0.x); a[1] = (short)f2bf(x0.y); a[2] = (short)f2bf(x0.z); a[3] = (short)f2bf(x0.w);
    a[4] = (short)f2bf(x1.x); a[5] = (short)f2bf(x1.y); a[6] = (short)f2bf(x1.z); a[7] = (short)f2bf(x1.w);
    af[s] = a;
  }

  int row_c = rt * 128 + wave * 16 + lg * 4;
  for (int et = 0; et < 2; ++et) {
    if (et) __syncthreads();   // previous-pass readers done before overwriting wl
    const float* Wsrc = Wf + (size_t)et * 128 * HID;
    // stage W half: f32 load -> cvt_pk bf16 -> swizzled LDS (same layout as before)
#pragma unroll
    for (int i = 0; i < 8; i++) {
      int c = i * 512 + tid;           // 16B bf16 chunk index
      int e = c >> 5;
      int perm = (c & 31) ^ (e & 7);   // chunk permutation within row
      const float* src = Wsrc + e * HID + perm * 8;
      float4 a0 = *(const float4*)(src);
      float4 a1 = *(const float4*)(src + 4);
      unsigned r0, r1, r2, r3;
      asm("v_cvt_pk_bf16_f32 %0, %1, %2" : "=v"(r0) : "v"(a0.x), "v"(a0.y));
      asm("v_cvt_pk_bf16_f32 %0, %1, %2" : "=v"(r1) : "v"(a0.z), "v"(a0.w));
      asm("v_cvt_pk_bf16_f32 %0, %1, %2" : "=v"(r2) : "v"(a1.x), "v"(a1.y));
      asm("v_cvt_pk_bf16_f32 %0, %1, %2" : "=v"(r3) : "v"(a1.z), "v"(a1.w));
      uint4 w; w.x = r0; w.y = r1; w.z = r2; w.w = r3;
      *(uint4*)(wl + c * 16) = w;
    }
    __syncthreads();

#pragma unroll
    for (int eo = 0; eo < 8; eo++) {
      f32x4 acc = (f32x4){0.f, 0.f, 0.f, 0.f};
      int eL = eo * 16 + lr;
#pragma unroll
      for (int sl = 0; sl < 8; sl++) {
        bf16x8 bfr = *(const bf16x8*)(wl + eL * 512 + (((sl * 4 + lg) ^ (eL & 7)) << 4));
        acc = __builtin_amdgcn_mfma_f32_16x16x32_bf16(af[sl], bfr, acc, 0, 0, 0);
      }
      int e = et * 128 + eo * 16 + lr;
      float bv_ = bias[e];
      if (mat < 2) {
        unsigned short* dst = (mat == 0 ? Qb : Kr) + (size_t)(b * SQL) * HID;
#pragma unroll
        for (int i = 0; i < 4; i++)
          dst[(size_t)(row_c + i) * HID + e] = f2bf(acc[i] + bv_);
      } else {
        // fragment-major V: jb = 4*((row_c>>4)&1), dt = et*8+eo
        int jb = 4 * ((row_c >> 4) & 1);
        size_t frag = (size_t)b * 1024 + (size_t)(row_c >> 5) * 16 + (et * 8 + eo);
        ushort4 v;
        v.x = f2bf(acc[0] + bv_); v.y = f2bf(acc[1] + bv_);
        v.z = f2bf(acc[2] + bv_); v.w = f2bf(acc[3] + bv_);
        *(ushort4*)(VFo + frag * 512 + (lr + 16 * lg) * 8 + jb) = v;
      }
    }
  }
}

// ---------- A: flash attention; K transposed-on-stage from row-major, V frag-major ----------
__global__ __launch_bounds__(256, 2) void attn_kernel(
    const unsigned short* __restrict__ Qb, const unsigned short* __restrict__ Kr,
    const char* __restrict__ VF, unsigned short* __restrict__ Op,
    float* __restrict__ Ml) {
  extern __shared__ char smem[];  // KA[16K] KB[16K] VA[16K] VB[16K]
  int tid = threadIdx.x;
  int wave = tid >> 6, lane = tid & 63, l15 = lane & 15, g = lane >> 4;
  int L = (blockIdx.x & 7) * 64 + (blockIdx.x >> 3);  // XCD x owns batch x
  int b = L >> 6, sp = (L >> 4) & 3, qt = L & 15;
  int q0 = qt * 128 + wave * 32;   // wave owns q0..q0+31 (2 tiles of 16)

  const char* Kr0 = (const char*)(Kr + ((size_t)b * SKV + (size_t)sp * KPB) * HID);
  const char* Vs0 = VF + ((size_t)(b * 64 + sp * 16)) * 16384;

  // K transpose-on-stage source offsets (frag-major dest = linear chunk order):
  int offK[4];
#pragma unroll
  for (int i = 0; i < 4; i++) {
    int c = i * 256 + tid;
    int fc = c >> 6, cidx = c & 63;
    int half = fc >> 3, s = fc & 7;
    int l15c = cidx & 15, gc = cidx >> 4;
    offK[i] = (half * 16 + l15c) * (HID * 2) + s * 64 + gc * 16;
  }

  auto stage = [&](int t, char* kb, char* vb) {
    const char* Ks = Kr0 + (size_t)t * (KVB * HID * 2);
    const char* Vs = Vs0 + (size_t)t * 16384;
#pragma unroll
    for (int i = 0; i < 4; i++)
      __builtin_amdgcn_global_load_lds(
          (const __attribute__((address_space(1))) unsigned int*)(Ks + offK[i]),
          (__attribute__((address_space(3))) unsigned int*)(kb + (i * 256 + tid) * 16),
          16, 0, 0);
#pragma unroll
    for (int i = 0; i < 4; i++)
      __builtin_amdgcn_global_load_lds(
          (const __attribute__((address_space(1))) unsigned int*)(Vs + i * 4096 + tid * 16),
          (__attribute__((address_space(3))) unsigned int*)(vb + i * 4096 + tid * 16),
          16, 0, 0);
  };

  // Q fragments for both tiles: lane(q=l15,g) holds Q[q][s*32+g*8..+7]
  bf16x8 qfa[8], qfb[8];
  {
    const unsigned short* qa = Qb + ((size_t)(b * SQL + q0 + l15)) * HID + g * 8;
    const unsigned short* qb2 = qa + 16 * HID;
#pragma unroll
    for (int s = 0; s < 8; s++) {
      qfa[s] = *(const bf16x8*)(qa + s * 32);
      qfb[s] = *(const bf16x8*)(qb2 + s * 32);
    }
  }

  f32x4 acc0[16], acc1[16];  // C[row=d_local=g*4+i][col=q=l15] per d-tile, per q-tile
#pragma unroll
  for (int dt = 0; dt < 16; dt++) {
    acc0[dt] = (f32x4){0.f, 0.f, 0.f, 0.f};
    acc1[dt] = (f32x4){0.f, 0.f, 0.f, 0.f};
  }
  float m0 = -1e30f, l0 = 0.f, m1 = -1e30f, l1 = 0.f;  // l per-lane partial; reduced in epilogue
  const float kC = 1.44269504088896341f / 11.3137084989847604f;  // log2(e)/sqrt(128)

  auto step = [&](const char* kb, const char* vb) {
    const char* kbl = kb + lane * 16;
    const char* vbl = vb + lane * 16;
    // QK^T swapped; frag-major reads: base + imm only
    f32x4 p0a = (f32x4){0.f,0.f,0.f,0.f}, p1a = (f32x4){0.f,0.f,0.f,0.f};
    f32x4 p0b = (f32x4){0.f,0.f,0.f,0.f}, p1b = (f32x4){0.f,0.f,0.f,0.f};
    __builtin_amdgcn_s_setprio(1);
#pragma unroll
    for (int s = 0; s < 8; s++) {
      bf16x8 kf0 = *(const bf16x8*)(kbl + s * 1024);
      bf16x8 kf1 = *(const bf16x8*)(kbl + (8 + s) * 1024);
      p0a = __builtin_amdgcn_mfma_f32_16x16x32_bf16(kf0, qfa[s], p0a, 0, 0, 0);
      p1a = __builtin_amdgcn_mfma_f32_16x16x32_bf16(kf1, qfa[s], p1a, 0, 0, 0);
      p0b = __builtin_amdgcn_mfma_f32_16x16x32_bf16(kf0, qfb[s], p0b, 0, 0, 0);
      p1b = __builtin_amdgcn_mfma_f32_16x16x32_bf16(kf1, qfb[s], p1b, 0, 0, 0);
    }
    __builtin_amdgcn_s_setprio(0);

    // online softmax, lane-local max fast path (full shfl reduce only when rescaling)
    float ta = fmaxf(fmaxf(fmaxf(p0a[0], p0a[1]), fmaxf(p0a[2], p0a[3])),
                     fmaxf(fmaxf(p1a[0], p1a[1]), fmaxf(p1a[2], p1a[3])));
    float tb = fmaxf(fmaxf(fmaxf(p0b[0], p0b[1]), fmaxf(p0b[2], p0b[3])),
                     fmaxf(fmaxf(p1b[0], p1b[1]), fmaxf(p1b[2], p1b[3])));
    if (!__all(ta * kC <= m0 + 8.0f)) {
      float tf = fmaxf(ta, __shfl_xor(ta, 16, 64));
      tf = fmaxf(tf, __shfl_xor(tf, 32, 64));
      float mn = fmaxf(m0, tf * kC);
      float al = exp2f(m0 - mn);
      l0 *= al; m0 = mn;
#pragma unroll
      for (int dt = 0; dt < 16; dt++)
#pragma unroll
        for (int i = 0; i < 4; i++) acc0[dt][i] *= al;
    }
    if (!__all(tb * kC <= m1 + 8.0f)) {
      float tf = fmaxf(tb, __shfl_xor(tb, 16, 64));
      tf = fmaxf(tf, __shfl_xor(tf, 32, 64));
      float mn = fmaxf(m1, tf * kC);
      float al = exp2f(m1 - mn);
      l1 *= al; m1 = mn;
#pragma unroll
      for (int dt = 0; dt < 16; dt++)
#pragma unroll
        for (int i = 0; i < 4; i++) acc1[dt][i] *= al;
    }
#pragma unroll
    for (int i = 0; i < 4; i++) {
      p0a[i] = exp2f(fmaf(p0a[i], kC, -m0)); p1a[i] = exp2f(fmaf(p1a[i], kC, -m0));
      p0b[i] = exp2f(fmaf(p0b[i], kC, -m1)); p1b[i] = exp2f(fmaf(p1b[i], kC, -m1));
    }
    // per-lane partial sums; cross-lane reduction deferred to epilogue
    l0 += (p0a[0] + p0a[1]) + (p0a[2] + p0a[3]) + (p1a[0] + p1a[1]) + (p1a[2] + p1a[3]);
    l1 += (p0b[0] + p0b[1]) + (p0b[2] + p0b[3]) + (p1b[0] + p1b[1]) + (p1b[2] + p1b[3]);

    // P -> PV B-fragments directly (keys lane-local in kappa order)
    unsigned wa0, wa1, wa2, wa3, wb0, wb1, wb2, wb3;
    asm("v_cvt_pk_bf16_f32 %0, %1, %2" : "=v"(wa0) : "v"(p0a[0]), "v"(p0a[1]));
    asm("v_cvt_pk_bf16_f32 %0, %1, %2" : "=v"(wa1) : "v"(p0a[2]), "v"(p0a[3]));
    asm("v_cvt_pk_bf16_f32 %0, %1, %2" : "=v"(wa2) : "v"(p1a[0]), "v"(p1a[1]));
    asm("v_cvt_pk_bf16_f32 %0, %1, %2" : "=v"(wa3) : "v"(p1a[2]), "v"(p1a[3]));
    asm("v_cvt_pk_bf16_f32 %0, %1, %2" : "=v"(wb0) : "v"(p0b[0]), "v"(p0b[1]));
    asm("v_cvt_pk_bf16_f32 %0, %1, %2" : "=v"(wb1) : "v"(p0b[2]), "v"(p0b[3]));
    asm("v_cvt_pk_bf16_f32 %0, %1, %2" : "=v"(wb2) : "v"(p1b[0]), "v"(p1b[1]));
    asm("v_cvt_pk_bf16_f32 %0, %1, %2" : "=v"(wb3) : "v"(p1b[2]), "v"(p1b[3]));
    union { unsigned u[4]; bf16x8 v; } pa, pb;
    pa.u[0] = wa0; pa.u[1] = wa1; pa.u[2] = wa2; pa.u[3] = wa3;
    pb.u[0] = wb0; pb.u[1] = wb1; pb.u[2] = wb2; pb.u[3] = wb3;

    // PV swapped: frag-major V reads (base + imm); each read feeds both q-tiles
    __builtin_amdgcn_s_setprio(1);
#pragma unroll
    for (int dt = 0; dt < 16; dt++) {
      bf16x8 vf = *(const bf16x8*)(vbl + dt * 1024);
      acc0[dt] = __builtin_amdgcn_mfma_f32_16x16x32_bf16(vf, pa.v, acc0[dt], 0, 0, 0);
      acc1[dt] = __builtin_amdgcn_mfma_f32_16x16x32_bf16(vf, pb.v, acc1[dt], 0, 0, 0);
    }
    __builtin_amdgcn_s_setprio(0);
  };

  stage(0, smem, smem + 32768);
  __syncthreads();
  for (int t = 0; t < NT; t++) {
    char* kb = smem + (t & 1) * 16384;
    char* vb = smem + 32768 + (t & 1) * 16384;
    if (t + 1 < NT)
      stage(t + 1, smem + ((t + 1) & 1) * 16384, smem + 32768 + ((t + 1) & 1) * 16384);
    step(kb, vb);
    __syncthreads();  // drain lands after compute; 2nd block/CU hides the rest
  }

  // epilogue: reduce deferred l partials across the 4 q-replicas
  l0 += __shfl_xor(l0, 16, 64); l0 += __shfl_xor(l0, 32, 64);
  l1 += __shfl_xor(l1, 16, 64); l1 += __shfl_xor(l1, 32, 64);

  size_t rowA = (size_t)b * SQL + q0 + l15;
  size_t rowB = rowA + 16;
  if (g == 0) {
    float2 mlA; mlA.x = m0; mlA.y = l0;
    float2 mlB; mlB.x = m1; mlB.y = l1;
    *(float2*)(Ml + ((size_t)sp * NROW + rowA) * 2) = mlA;
    *(float2*)(Ml + ((size_t)sp * NROW + rowB) * 2) = mlB;
  }
  float li0 = 1.0f / l0, li1 = 1.0f / l1;
  unsigned short* oA = Op + ((size_t)sp * NROW + rowA) * HID;
  unsigned short* oB = Op + ((size_t)sp * NROW + rowB) * HID;
#pragma unroll
  for (int dt = 0; dt < 16; dt++) {
    ushort4 v0, v1;
    union { _Float16 hf; unsigned short u; } c;
    c.hf = (_Float16)(acc0[dt][0] * li0); v0.x = c.u;
    c.hf = (_Float16)(acc0[dt][1] * li0); v0.y = c.u;
    c.hf = (_Float16)(acc0[dt][2] * li0); v0.z = c.u;
    c.hf = (_Float16)(acc0[dt][3] * li0); v0.w = c.u;
    c.hf = (_Float16)(acc1[dt][0] * li1); v1.x = c.u;
    c.hf = (_Float16)(acc1[dt][1] * li1); v1.y = c.u;
    c.hf = (_Float16)(acc1[dt][2] * li1); v1.z = c.u;
    c.hf = (_Float16)(acc1[dt][3] * li1); v1.w = c.u;
    *(ushort4*)(oA + dt * 16 + g * 4) = v0;
    *(ushort4*)(oB + dt * 16 + g * 4) = v1;
  }
}

// ---------- C: combine split partials ----------
__global__ __launch_bounds__(256) void comb_kernel(const unsigned short* __restrict__ Op,
                                                   const float* __restrict__ Ml,
                                                   float* __restrict__ out) {
  int idx = blockIdx.x * 256 + threadIdx.x;
  int row = idx >> 6;
  int d0 = (idx & 63) << 2;
  float mv[SPLIT], lv[SPLIT];
#pragma unroll
  for (int s = 0; s < SPLIT; s++) {
    float2 ml = *(const float2*)(Ml + ((size_t)s * NROW + row) * 2);
    mv[s] = ml.x; lv[s] = ml.y;
  }
  float M = mv[0];
#pragma unroll
  for (int s = 1; s < SPLIT; s++) M = fmaxf(M, mv[s]);
  float W = 0.f, w[SPLIT];
#pragma unroll
  for (int s = 0; s < SPLIT; s++) { w[s] = lv[s] * exp2f(mv[s] - M); W += w[s]; }
  float wi = 1.0f / W;
  float o0 = 0.f, o1 = 0.f, o2 = 0.f, o3 = 0.f;
#pragma unroll
  for (int s = 0; s < SPLIT; s++) {
    ushort4 u = *(const ushort4*)(Op + ((size_t)s * NROW + row) * HID + d0);
    union { unsigned short us; _Float16 hf; } c0, c1, c2, c3;
    c0.us = u.x; c1.us = u.y; c2.us = u.z; c3.us = u.w;
    o0 += w[s] * (float)c0.hf; o1 += w[s] * (float)c1.hf;
    o2 += w[s] * (float)c2.hf; o3 += w[s] * (float)c3.hf;
  }
  float4 res; res.x = o0 * wi; res.y = o1 * wi; res.z = o2 * wi; res.w = o3 * wi;
  *(float4*)(out + (size_t)row * HID + d0) = res;
}

extern "C" void kernel_launch(void* const* d_in, const int* in_sizes, int n_in,
                              void* d_out, int out_size, void* d_ws, size_t ws_size,
                              hipStream_t stream) {
  const float* query = (const float*)d_in[0];
  const float* key   = (const float*)d_in[1];
  const float* value = (const float*)d_in[2];
  const float* Wq = (const float*)d_in[3];
  const float* bq = (const float*)d_in[4];
  const float* Wk = (const float*)d_in[5];
  const float* bk = (const float*)d_in[6];
  const float* Wv = (const float*)d_in[7];
  const float* bv = (const float*)d_in[8];

  char* ws = (char*)d_ws;
  unsigned short* Qb  = (unsigned short*)ws;
  unsigned short* Kr  = Qb + (size_t)NB * SQL * HID;                // row-major K
  unsigned short* VF  = Kr + (size_t)NB * SKV * HID;                // fragment-major V
  unsigned short* Op  = VF + (size_t)NB * HID * SKV;                // f16 partials
  float* Ml = (float*)(Op + (size_t)SPLIT * NROW * HID);            // (m,l)

  hipLaunchKernelGGL(proj_kernel, dim3(384), dim3(512), 0, stream,
                     query, key, value, Wq, Wk, Wv, bq, bk, bv, Qb, Kr, VF);
  hipLaunchKernelGGL(attn_kernel, dim3(512), dim3(256), 65536, stream,
                     Qb, Kr, (const char*)VF, Op, Ml);
  hipLaunchKernelGGL(comb_kernel, dim3(4096), dim3(256), 0, stream, Op, Ml, (float*)d_out);
}

// Round 17
// 87.647 us; speedup vs baseline: 1.0292x; 1.0292x over previous
//
#include <hip/hip_runtime.h>

#define HID 256
#define NB 8
#define SQL 2048
#define SKV 2048
#define SPLIT 4
#define KPB (SKV / SPLIT)   // 512 keys per (b,split) stream
#define KVB 32              // keys per staged tile
#define NT (KPB / KVB)      // 16 steps
#define NROW (NB * SQL)     // 16384 rows

typedef __attribute__((ext_vector_type(8))) short bf16x8;
typedef __attribute__((ext_vector_type(4))) float f32x4;

static __device__ __forceinline__ unsigned short f2bf(float x) {
  union { float f; unsigned int u; } v; v.f = x;
  unsigned int r = v.u + 0x7FFFu + ((v.u >> 16) & 1u);
  return (unsigned short)(r >> 16);
}

// ---------- P0: convert weight matrices to bf16 ----------
__global__ void wconv_kernel(const float* __restrict__ Wq, const float* __restrict__ Wk,
                             const float* __restrict__ Wv, unsigned short* __restrict__ out) {
  int i = blockIdx.x * blockDim.x + threadIdx.x;
  if (i >= 3 * HID * HID) return;
  const float* src = (i < HID * HID) ? Wq : (i < 2 * HID * HID ? Wk : Wv);
  out[i] = f2bf(src[i & (HID * HID - 1)]);
}

// ---------- P1: QKV projection. Q,K row-major; V fragment-major (kappa key order) ----------
// VF frag(b, tile, dt): lane(l15,g), j: V[key = tile*32 + 4g + (j&3) + 16*(j>>2)][dt*16 + l15]
__global__ __launch_bounds__(512, 2) void proj_kernel(
    const float* __restrict__ query, const float* __restrict__ key, const float* __restrict__ value,
    const unsigned short* __restrict__ Wb,
    const float* __restrict__ bq, const float* __restrict__ bk, const float* __restrict__ bv,
    unsigned short* __restrict__ Qb, unsigned short* __restrict__ Kr, unsigned short* __restrict__ VFo) {
  __shared__ __align__(16) char wl[65536];
  int tid = threadIdx.x;
  int wave = tid >> 6, lane = tid & 63, lr = lane & 15, lg = lane >> 4;
  int blk = blockIdx.x;        // 384 blocks
  int mat = blk >> 7;          // 0:Q 1:K 2:V
  int rem = blk & 127;
  int b = rem >> 4;
  int rt = rem & 15;

  const float* X = (mat == 0) ? query : (mat == 1 ? key : value);
  const float* bias = (mat == 0) ? bq : (mat == 1 ? bk : bv);

  // A fragments once: 16 rows per wave, f32 -> bf16
  int row_a = rt * 128 + wave * 16 + lr;
  const float* xrow = X + ((size_t)(b * SQL + row_a)) * HID;
  bf16x8 af[8];
#pragma unroll
  for (int s = 0; s < 8; s++) {
    const float4* p = (const float4*)(xrow + s * 32 + lg * 8);
    float4 x0 = p[0], x1 = p[1];
    bf16x8 a;
    a[0] = (short)f2bf(x0.x); a[1] = (short)f2bf(x0.y); a[2] = (short)f2bf(x0.z); a[3] = (short)f2bf(x0.w);
    a[4] = (short)f2bf(x1.x); a[5] = (short)f2bf(x1.y); a[6] = (short)f2bf(x1.z); a[7] = (short)f2bf(x1.w);
    af[s] = a;
  }

  int row_c = rt * 128 + wave * 16 + lg * 4;
  for (int et = 0; et < 2; ++et) {
    if (et) __syncthreads();   // previous-pass readers done before overwriting wl
    const char* Wsrc = (const char*)(Wb + mat * HID * HID + et * 128 * HID);
#pragma unroll
    for (int i = 0; i < 8; i++) {
      int c = i * 512 + tid;
      int e = c >> 5;
      int glo = e * 512 + (((c & 31) ^ (e & 7)) << 4);
      __builtin_amdgcn_global_load_lds(
          (const __attribute__((address_space(1))) unsigned int*)(Wsrc + glo),
          (__attribute__((address_space(3))) unsigned int*)(wl + c * 16), 16, 0, 0);
    }
    __syncthreads();

#pragma unroll
    for (int eo = 0; eo < 8; eo++) {
      f32x4 acc = (f32x4){0.f, 0.f, 0.f, 0.f};
      int eL = eo * 16 + lr;
#pragma unroll
      for (int sl = 0; sl < 8; sl++) {
        bf16x8 bfr = *(const bf16x8*)(wl + eL * 512 + (((sl * 4 + lg) ^ (eL & 7)) << 4));
        acc = __builtin_amdgcn_mfma_f32_16x16x32_bf16(af[sl], bfr, acc, 0, 0, 0);
      }
      int e = et * 128 + eo * 16 + lr;
      float bv_ = bias[e];
      if (mat < 2) {
        unsigned short* dst = (mat == 0 ? Qb : Kr) + (size_t)(b * SQL) * HID;
#pragma unroll
        for (int i = 0; i < 4; i++)
          dst[(size_t)(row_c + i) * HID + e] = f2bf(acc[i] + bv_);
      } else {
        // fragment-major V: jb = 4*((row_c>>4)&1), dt = et*8+eo
        int jb = 4 * ((row_c >> 4) & 1);
        size_t frag = (size_t)b * 1024 + (size_t)(row_c >> 5) * 16 + (et * 8 + eo);
        ushort4 v;
        v.x = f2bf(acc[0] + bv_); v.y = f2bf(acc[1] + bv_);
        v.z = f2bf(acc[2] + bv_); v.w = f2bf(acc[3] + bv_);
        *(ushort4*)(VFo + frag * 512 + (lr + 16 * lg) * 8 + jb) = v;
      }
    }
  }
}

// ---------- A: flash attention; K transposed-on-stage from row-major, V frag-major ----------
__global__ __launch_bounds__(256, 2) void attn_kernel(
    const unsigned short* __restrict__ Qb, const unsigned short* __restrict__ Kr,
    const char* __restrict__ VF, unsigned short* __restrict__ Op,
    float* __restrict__ Ml) {
  extern __shared__ char smem[];  // KA[16K] KB[16K] VA[16K] VB[16K]
  int tid = threadIdx.x;
  int wave = tid >> 6, lane = tid & 63, l15 = lane & 15, g = lane >> 4;
  int L = (blockIdx.x & 7) * 64 + (blockIdx.x >> 3);  // XCD x owns batch x
  int b = L >> 6, sp = (L >> 4) & 3, qt = L & 15;
  int q0 = qt * 128 + wave * 32;   // wave owns q0..q0+31 (2 tiles of 16)

  const char* Kr0 = (const char*)(Kr + ((size_t)b * SKV + (size_t)sp * KPB) * HID);
  const char* Vs0 = VF + ((size_t)(b * 64 + sp * 16)) * 16384;

  // K transpose-on-stage source offsets (frag-major dest = linear chunk order):
  // chunk c: frag fc=c>>6 (half=fc>>3, s=fc&7), lane cidx=c&63 (l15c=cidx&15, gc=cidx>>4)
  // src = K[half*16 + l15c][s*32 + gc*8 ..+7]  (16B, 16 full 64B lines per wave-instr)
  int offK[4];
#pragma unroll
  for (int i = 0; i < 4; i++) {
    int c = i * 256 + tid;
    int fc = c >> 6, cidx = c & 63;
    int half = fc >> 3, s = fc & 7;
    int l15c = cidx & 15, gc = cidx >> 4;
    offK[i] = (half * 16 + l15c) * (HID * 2) + s * 64 + gc * 16;
  }

  auto stage = [&](int t, char* kb, char* vb) {
    const char* Ks = Kr0 + (size_t)t * (KVB * HID * 2);
    const char* Vs = Vs0 + (size_t)t * 16384;
#pragma unroll
    for (int i = 0; i < 4; i++)
      __builtin_amdgcn_global_load_lds(
          (const __attribute__((address_space(1))) unsigned int*)(Ks + offK[i]),
          (__attribute__((address_space(3))) unsigned int*)(kb + (i * 256 + tid) * 16),
          16, 0, 0);
#pragma unroll
    for (int i = 0; i < 4; i++)
      __builtin_amdgcn_global_load_lds(
          (const __attribute__((address_space(1))) unsigned int*)(Vs + i * 4096 + tid * 16),
          (__attribute__((address_space(3))) unsigned int*)(vb + i * 4096 + tid * 16),
          16, 0, 0);
  };

  // Q fragments for both tiles: lane(q=l15,g) holds Q[q][s*32+g*8..+7]
  bf16x8 qfa[8], qfb[8];
  {
    const unsigned short* qa = Qb + ((size_t)(b * SQL + q0 + l15)) * HID + g * 8;
    const unsigned short* qb2 = qa + 16 * HID;
#pragma unroll
    for (int s = 0; s < 8; s++) {
      qfa[s] = *(const bf16x8*)(qa + s * 32);
      qfb[s] = *(const bf16x8*)(qb2 + s * 32);
    }
  }

  f32x4 acc0[16], acc1[16];  // C[row=d_local=g*4+i][col=q=l15] per d-tile, per q-tile
#pragma unroll
  for (int dt = 0; dt < 16; dt++) {
    acc0[dt] = (f32x4){0.f, 0.f, 0.f, 0.f};
    acc1[dt] = (f32x4){0.f, 0.f, 0.f, 0.f};
  }
  float m0 = -1e30f, l0 = 0.f, m1 = -1e30f, l1 = 0.f;  // l per-lane partial; reduced in epilogue
  const float kC = 1.44269504088896341f / 11.3137084989847604f;  // log2(e)/sqrt(128)

  auto step = [&](const char* kb, const char* vb) {
    const char* kbl = kb + lane * 16;
    const char* vbl = vb + lane * 16;
    // QK^T swapped; frag-major reads: base + imm only
    f32x4 p0a = (f32x4){0.f,0.f,0.f,0.f}, p1a = (f32x4){0.f,0.f,0.f,0.f};
    f32x4 p0b = (f32x4){0.f,0.f,0.f,0.f}, p1b = (f32x4){0.f,0.f,0.f,0.f};
    __builtin_amdgcn_s_setprio(1);
#pragma unroll
    for (int s = 0; s < 8; s++) {
      bf16x8 kf0 = *(const bf16x8*)(kbl + s * 1024);
      bf16x8 kf1 = *(const bf16x8*)(kbl + (8 + s) * 1024);
      p0a = __builtin_amdgcn_mfma_f32_16x16x32_bf16(kf0, qfa[s], p0a, 0, 0, 0);
      p1a = __builtin_amdgcn_mfma_f32_16x16x32_bf16(kf1, qfa[s], p1a, 0, 0, 0);
      p0b = __builtin_amdgcn_mfma_f32_16x16x32_bf16(kf0, qfb[s], p0b, 0, 0, 0);
      p1b = __builtin_amdgcn_mfma_f32_16x16x32_bf16(kf1, qfb[s], p1b, 0, 0, 0);
    }
    __builtin_amdgcn_s_setprio(0);

    // online softmax, lane-local max fast path (full shfl reduce only when rescaling)
    float ta = fmaxf(fmaxf(fmaxf(p0a[0], p0a[1]), fmaxf(p0a[2], p0a[3])),
                     fmaxf(fmaxf(p1a[0], p1a[1]), fmaxf(p1a[2], p1a[3])));
    float tb = fmaxf(fmaxf(fmaxf(p0b[0], p0b[1]), fmaxf(p0b[2], p0b[3])),
                     fmaxf(fmaxf(p1b[0], p1b[1]), fmaxf(p1b[2], p1b[3])));
    if (!__all(ta * kC <= m0 + 8.0f)) {
      float tf = fmaxf(ta, __shfl_xor(ta, 16, 64));
      tf = fmaxf(tf, __shfl_xor(tf, 32, 64));
      float mn = fmaxf(m0, tf * kC);
      float al = exp2f(m0 - mn);
      l0 *= al; m0 = mn;
#pragma unroll
      for (int dt = 0; dt < 16; dt++)
#pragma unroll
        for (int i = 0; i < 4; i++) acc0[dt][i] *= al;
    }
    if (!__all(tb * kC <= m1 + 8.0f)) {
      float tf = fmaxf(tb, __shfl_xor(tb, 16, 64));
      tf = fmaxf(tf, __shfl_xor(tf, 32, 64));
      float mn = fmaxf(m1, tf * kC);
      float al = exp2f(m1 - mn);
      l1 *= al; m1 = mn;
#pragma unroll
      for (int dt = 0; dt < 16; dt++)
#pragma unroll
        for (int i = 0; i < 4; i++) acc1[dt][i] *= al;
    }
#pragma unroll
    for (int i = 0; i < 4; i++) {
      p0a[i] = exp2f(fmaf(p0a[i], kC, -m0)); p1a[i] = exp2f(fmaf(p1a[i], kC, -m0));
      p0b[i] = exp2f(fmaf(p0b[i], kC, -m1)); p1b[i] = exp2f(fmaf(p1b[i], kC, -m1));
    }
    // per-lane partial sums; cross-lane reduction deferred to epilogue
    l0 += (p0a[0] + p0a[1]) + (p0a[2] + p0a[3]) + (p1a[0] + p1a[1]) + (p1a[2] + p1a[3]);
    l1 += (p0b[0] + p0b[1]) + (p0b[2] + p0b[3]) + (p1b[0] + p1b[1]) + (p1b[2] + p1b[3]);

    // P -> PV B-fragments directly (keys lane-local in kappa order)
    unsigned wa0, wa1, wa2, wa3, wb0, wb1, wb2, wb3;
    asm("v_cvt_pk_bf16_f32 %0, %1, %2" : "=v"(wa0) : "v"(p0a[0]), "v"(p0a[1]));
    asm("v_cvt_pk_bf16_f32 %0, %1, %2" : "=v"(wa1) : "v"(p0a[2]), "v"(p0a[3]));
    asm("v_cvt_pk_bf16_f32 %0, %1, %2" : "=v"(wa2) : "v"(p1a[0]), "v"(p1a[1]));
    asm("v_cvt_pk_bf16_f32 %0, %1, %2" : "=v"(wa3) : "v"(p1a[2]), "v"(p1a[3]));
    asm("v_cvt_pk_bf16_f32 %0, %1, %2" : "=v"(wb0) : "v"(p0b[0]), "v"(p0b[1]));
    asm("v_cvt_pk_bf16_f32 %0, %1, %2" : "=v"(wb1) : "v"(p0b[2]), "v"(p0b[3]));
    asm("v_cvt_pk_bf16_f32 %0, %1, %2" : "=v"(wb2) : "v"(p1b[0]), "v"(p1b[1]));
    asm("v_cvt_pk_bf16_f32 %0, %1, %2" : "=v"(wb3) : "v"(p1b[2]), "v"(p1b[3]));
    union { unsigned u[4]; bf16x8 v; } pa, pb;
    pa.u[0] = wa0; pa.u[1] = wa1; pa.u[2] = wa2; pa.u[3] = wa3;
    pb.u[0] = wb0; pb.u[1] = wb1; pb.u[2] = wb2; pb.u[3] = wb3;

    // PV swapped: frag-major V reads (base + imm); each read feeds both q-tiles
    __builtin_amdgcn_s_setprio(1);
#pragma unroll
    for (int dt = 0; dt < 16; dt++) {
      bf16x8 vf = *(const bf16x8*)(vbl + dt * 1024);
      acc0[dt] = __builtin_amdgcn_mfma_f32_16x16x32_bf16(vf, pa.v, acc0[dt], 0, 0, 0);
      acc1[dt] = __builtin_amdgcn_mfma_f32_16x16x32_bf16(vf, pb.v, acc1[dt], 0, 0, 0);
    }
    __builtin_amdgcn_s_setprio(0);
  };

  stage(0, smem, smem + 32768);
  __syncthreads();
  for (int t = 0; t < NT; t++) {
    char* kb = smem + (t & 1) * 16384;
    char* vb = smem + 32768 + (t & 1) * 16384;
    if (t + 1 < NT)
      stage(t + 1, smem + ((t + 1) & 1) * 16384, smem + 32768 + ((t + 1) & 1) * 16384);
    step(kb, vb);
    __syncthreads();  // drain lands after compute; 2nd block/CU hides the rest
  }

  // epilogue: reduce deferred l partials across the 4 q-replicas
  l0 += __shfl_xor(l0, 16, 64); l0 += __shfl_xor(l0, 32, 64);
  l1 += __shfl_xor(l1, 16, 64); l1 += __shfl_xor(l1, 32, 64);

  size_t rowA = (size_t)b * SQL + q0 + l15;
  size_t rowB = rowA + 16;
  if (g == 0) {
    float2 mlA; mlA.x = m0; mlA.y = l0;
    float2 mlB; mlB.x = m1; mlB.y = l1;
    *(float2*)(Ml + ((size_t)sp * NROW + rowA) * 2) = mlA;
    *(float2*)(Ml + ((size_t)sp * NROW + rowB) * 2) = mlB;
  }
  float li0 = 1.0f / l0, li1 = 1.0f / l1;
  unsigned short* oA = Op + ((size_t)sp * NROW + rowA) * HID;
  unsigned short* oB = Op + ((size_t)sp * NROW + rowB) * HID;
#pragma unroll
  for (int dt = 0; dt < 16; dt++) {
    ushort4 v0, v1;
    union { _Float16 hf; unsigned short u; } c;
    c.hf = (_Float16)(acc0[dt][0] * li0); v0.x = c.u;
    c.hf = (_Float16)(acc0[dt][1] * li0); v0.y = c.u;
    c.hf = (_Float16)(acc0[dt][2] * li0); v0.z = c.u;
    c.hf = (_Float16)(acc0[dt][3] * li0); v0.w = c.u;
    c.hf = (_Float16)(acc1[dt][0] * li1); v1.x = c.u;
    c.hf = (_Float16)(acc1[dt][1] * li1); v1.y = c.u;
    c.hf = (_Float16)(acc1[dt][2] * li1); v1.z = c.u;
    c.hf = (_Float16)(acc1[dt][3] * li1); v1.w = c.u;
    *(ushort4*)(oA + dt * 16 + g * 4) = v0;
    *(ushort4*)(oB + dt * 16 + g * 4) = v1;
  }
}

// ---------- C: combine split partials ----------
__global__ __launch_bounds__(256) void comb_kernel(const unsigned short* __restrict__ Op,
                                                   const float* __restrict__ Ml,
                                                   float* __restrict__ out) {
  int idx = blockIdx.x * 256 + threadIdx.x;
  int row = idx >> 6;
  int d0 = (idx & 63) << 2;
  float mv[SPLIT], lv[SPLIT];
#pragma unroll
  for (int s = 0; s < SPLIT; s++) {
    float2 ml = *(const float2*)(Ml + ((size_t)s * NROW + row) * 2);
    mv[s] = ml.x; lv[s] = ml.y;
  }
  float M = mv[0];
#pragma unroll
  for (int s = 1; s < SPLIT; s++) M = fmaxf(M, mv[s]);
  float W = 0.f, w[SPLIT];
#pragma unroll
  for (int s = 0; s < SPLIT; s++) { w[s] = lv[s] * exp2f(mv[s] - M); W += w[s]; }
  float wi = 1.0f / W;
  float o0 = 0.f, o1 = 0.f, o2 = 0.f, o3 = 0.f;
#pragma unroll
  for (int s = 0; s < SPLIT; s++) {
    ushort4 u = *(const ushort4*)(Op + ((size_t)s * NROW + row) * HID + d0);
    union { unsigned short us; _Float16 hf; } c0, c1, c2, c3;
    c0.us = u.x; c1.us = u.y; c2.us = u.z; c3.us = u.w;
    o0 += w[s] * (float)c0.hf; o1 += w[s] * (float)c1.hf;
    o2 += w[s] * (float)c2.hf; o3 += w[s] * (float)c3.hf;
  }
  float4 res; res.x = o0 * wi; res.y = o1 * wi; res.z = o2 * wi; res.w = o3 * wi;
  *(float4*)(out + (size_t)row * HID + d0) = res;
}

extern "C" void kernel_launch(void* const* d_in, const int* in_sizes, int n_in,
                              void* d_out, int out_size, void* d_ws, size_t ws_size,
                              hipStream_t stream) {
  const float* query = (const float*)d_in[0];
  const float* key   = (const float*)d_in[1];
  const float* value = (const float*)d_in[2];
  const float* Wq = (const float*)d_in[3];
  const float* bq = (const float*)d_in[4];
  const float* Wk = (const float*)d_in[5];
  const float* bk = (const float*)d_in[6];
  const float* Wv = (const float*)d_in[7];
  const float* bv = (const float*)d_in[8];

  char* ws = (char*)d_ws;
  unsigned short* Wb  = (unsigned short*)ws;                        // 393216 B
  unsigned short* Qb  = (unsigned short*)(ws + 393216);
  unsigned short* Kr  = Qb + (size_t)NB * SQL * HID;                // row-major K
  unsigned short* VF  = Kr + (size_t)NB * SKV * HID;                // fragment-major V
  unsigned short* Op  = VF + (size_t)NB * HID * SKV;                // f16 partials
  float* Ml = (float*)(Op + (size_t)SPLIT * NROW * HID);            // (m,l)

  hipLaunchKernelGGL(wconv_kernel, dim3(768), dim3(256), 0, stream, Wq, Wk, Wv, Wb);
  hipLaunchKernelGGL(proj_kernel, dim3(384), dim3(512), 0, stream,
                     query, key, value, Wb, bq, bk, bv, Qb, Kr, VF);
  hipLaunchKernelGGL(attn_kernel, dim3(512), dim3(256), 65536, stream,
                     Qb, Kr, (const char*)VF, Op, Ml);
  hipLaunchKernelGGL(comb_kernel, dim3(4096), dim3(256), 0, stream, Op, Ml, (float*)d_out);
}